// Round 3
// baseline (215.564 us; speedup 1.0000x reference)
//
#include <hip/hip_runtime.h>

// Problem constants
#define B_  32
#define C_  64
#define H_  64
#define W_  64
#define O_  128
#define LAT 64
#define HW  (H_*W_)
#define KJ  (O_*C_*9)      // 73728
#define KTOT 576           // C_*9, GEMM K per batch

typedef __bf16 bf16x8 __attribute__((ext_vector_type(8)));
typedef float  f32x4  __attribute__((ext_vector_type(4)));

// ---------------------------------------------------------------------------
// Stage 1: transpose x -> xT[b][h][w][c] bf16, plus per-(b,h,c) row sums.
// fp32 LDS tile with stride 65 (bank = (c+w)%32): writes 2-way, reads 2-way
// -> conflict-free. No atomics: partials to gap_part[h][b][c], reduced in mlp.
// ---------------------------------------------------------------------------
__global__ __launch_bounds__(256) void transpose_gap(const float* __restrict__ x,
                                                     __bf16* __restrict__ xT,
                                                     float* __restrict__ gap_part) {
    int bh = blockIdx.x, b = bh >> 6, h = bh & 63;
    __shared__ float lt[64 * 65];                 // 16.6 KB
    int t = threadIdx.x;
    int cc0 = t >> 4, w4 = (t & 15) * 4;

    #pragma unroll
    for (int i = 0; i < 4; i++) {
        int cc = cc0 + 16 * i;
        float4 v = *(const float4*)(x + (((size_t)(b * C_ + cc) * H_) + h) * W_ + w4);
        lt[cc * 65 + w4 + 0] = v.x;
        lt[cc * 65 + w4 + 1] = v.y;
        lt[cc * 65 + w4 + 2] = v.z;
        lt[cc * 65 + w4 + 3] = v.w;
        float s = (v.x + v.y) + (v.z + v.w);
        s += __shfl_xor(s, 1); s += __shfl_xor(s, 2);
        s += __shfl_xor(s, 4); s += __shfl_xor(s, 8);
        if ((t & 15) == 0) gap_part[h * 2048 + b * 64 + cc] = s;
    }
    __syncthreads();

    __bf16* dst = xT + ((size_t)(b * H_ + h) * W_) * C_;
    #pragma unroll
    for (int k = 0; k < 2; k++) {
        int chunk = t + k * 256;
        int w = chunk >> 3, c8 = chunk & 7;
        __bf16 g[8];
        #pragma unroll
        for (int i = 0; i < 8; i++) g[i] = (__bf16)lt[(c8 * 8 + i) * 65 + w];
        *(int4*)(dst + w * C_ + c8 * 8) = *(int4*)g;
    }
}

// ---------------------------------------------------------------------------
// Stage 2: gap reduction + two-layer MLP (fp32). One wave per batch.
// ---------------------------------------------------------------------------
__global__ __launch_bounds__(64) void mlp_kernel(const float* __restrict__ gap_part,
                                                 const float* __restrict__ W1,
                                                 const float* __restrict__ b1,
                                                 const float* __restrict__ W2,
                                                 const float* __restrict__ b2,
                                                 float* __restrict__ f2out) {
    int b = blockIdx.x, j = threadIdx.x;
    float s = 0.f;
    #pragma unroll 16
    for (int h = 0; h < 64; h++) s += gap_part[h * 2048 + b * 64 + j];  // coalesced
    __shared__ float g[LAT], f1[LAT];
    g[j] = s * (1.0f / (float)HW);
    __syncthreads();
    float acc = b1[j];
    #pragma unroll 8
    for (int l = 0; l < LAT; l++) acc = fmaf(g[l], W1[l * LAT + j], acc);
    f1[j] = fmaxf(acc, 0.f);
    __syncthreads();
    float acc2 = b2[j];
    #pragma unroll 8
    for (int l = 0; l < LAT; l++) acc2 = fmaf(f1[l], W2[l * LAT + j], acc2);
    f2out[b * LAT + j] = fmaxf(acc2, 0.f);
}

// ---------------------------------------------------------------------------
// Stage 3: kernel generator -> bf16 tap-major kbf[b][o][tap][c].
// One block per o (576 threads = 9 waves). Thread t owns source column
// j = o*576 + t (t = c*9 + tap): Wf reads coalesced. Layout shuffle goes
// through LDS so global writes are coalesced (was 2.36M scattered 2B stores).
// ---------------------------------------------------------------------------
#define KGP 600   // padded per-b LDS stride (elems)
__global__ __launch_bounds__(576) void kergen_kernel(const float* __restrict__ f2,
                                                     const float* __restrict__ Wf,
                                                     const float* __restrict__ bf,
                                                     __bf16* __restrict__ kbf) {
    int o = blockIdx.x, t = threadIdx.x;
    int j = o * KTOT + t;
    __shared__ __bf16 ltk[32 * KGP];              // 38.4 KB

    float acc[B_];
    float base = bf[j];
    #pragma unroll
    for (int bb = 0; bb < B_; bb++) acc[bb] = base;
    #pragma unroll 2
    for (int l = 0; l < LAT; l++) {
        float w = Wf[(size_t)l * KJ + j];          // coalesced
        #pragma unroll
        for (int bb = 0; bb < B_; bb++)
            acc[bb] = fmaf(f2[bb * LAT + l], w, acc[bb]);  // uniform -> s_load
    }
    int c = t / 9, tap = t - c * 9;
    #pragma unroll
    for (int bb = 0; bb < B_; bb++)
        ltk[bb * KGP + tap * 66 + c] = (__bf16)acc[bb];
    __syncthreads();
    int tapd = t >> 6, cd = t & 63;               // dest index t = tapd*64+cd
    #pragma unroll
    for (int bb = 0; bb < B_; bb++)
        kbf[(size_t)bb * KJ + o * KTOT + t] = ltk[bb * KGP + tapd * 66 + cd];
}

// ---------------------------------------------------------------------------
// Stage 4: implicit-GEMM MFMA conv. M=128 o, N=128 px (2 rows), K=576.
// A (ker) register-prefetched at depth 2 (3-buffer rotation) so the vmcnt
// wait lands ~2 k-steps (~200+ cyc) after issue -> L2 latency hidden.
// Targeted halo/OOB zeroing instead of full LDS memset (saves ~9 int4/thread
// and one barrier).
// ---------------------------------------------------------------------------
#define CPAD 72
#define ROWE (66 * CPAD)            // elems per LDS row slab

__global__ __launch_bounds__(256, 4) void conv_mfma(const __bf16* __restrict__ xT,
                                                    const __bf16* __restrict__ kbf,
                                                    float* __restrict__ out) {
    int b  = blockIdx.y;
    int h0 = blockIdx.x * 2;
    __shared__ __bf16 xs[4 * ROWE];               // 38016 B
    int tid = threadIdx.x;

    // zero halo columns w'=0 and w'=65 (all 4 rows): 64 int4 stores total
    if (tid < 64) {
        int r = tid >> 4, which = (tid >> 3) & 1, c8 = tid & 7;
        *(int4*)(xs + (r * 66 + which * 65) * CPAD + c8 * 8) = int4{0, 0, 0, 0};
    }
    // zero OOB rows (block-uniform branches; only edge blocks)
    if (h0 == 0) {
        for (int i = tid; i < ROWE / 8; i += 256)
            *(int4*)(xs + i * 8) = int4{0, 0, 0, 0};
    }
    if (h0 == H_ - 2) {
        for (int i = tid; i < ROWE / 8; i += 256)
            *(int4*)(xs + 3 * ROWE + i * 8) = int4{0, 0, 0, 0};
    }

    // stage rows h0-1 .. h0+2 (16B chunks, coalesced)
    #pragma unroll
    for (int i = 0; i < 8; i++) {
        int chunk = tid + i * 256;                // ((r*64)+w)*8 + c8
        int c8 = chunk & 7, w = (chunk >> 3) & 63, r = chunk >> 9;
        int hh = h0 - 1 + r;
        if ((unsigned)hh < (unsigned)H_) {
            int4 v = *(const int4*)(xT + ((size_t)(b * H_ + hh) * W_ + w) * C_ + c8 * 8);
            *(int4*)(xs + (r * 66 + w + 1) * CPAD + c8 * 8) = v;
        }
    }
    __syncthreads();

    int wave = tid >> 6, lane = tid & 63;
    int wi = wave >> 1, wj = wave & 1;            // 2x2 wave grid
    int l15 = lane & 15, quad = lane >> 4;

    const __bf16* Abase = kbf + ((size_t)b * O_ + wi * 64 + l15) * KTOT + quad * 8;

    f32x4 acc[4][4];
    #pragma unroll
    for (int mt = 0; mt < 4; mt++)
        #pragma unroll
        for (int nt = 0; nt < 4; nt++)
            acc[mt][nt] = (f32x4){0.f, 0.f, 0.f, 0.f};

    bf16x8 Abuf[3][4];
    #pragma unroll
    for (int mt = 0; mt < 4; mt++) {
        Abuf[0][mt] = *(const bf16x8*)(Abase + mt * 16 * KTOT);
        Abuf[1][mt] = *(const bf16x8*)(Abase + mt * 16 * KTOT + 32);
    }

    #pragma unroll
    for (int ks = 0; ks < 18; ks++) {
        if (ks < 16) {
            #pragma unroll
            for (int mt = 0; mt < 4; mt++)
                Abuf[(ks + 2) % 3][mt] =
                    *(const bf16x8*)(Abase + mt * 16 * KTOT + (ks + 2) * 32);
        }
        int tap = ks >> 1;                        // compile-time after unroll
        int kh = tap / 3, kw = tap - kh * 3;
        int c0 = (ks & 1) * 32;
        const __bf16* Bb = xs + ((wj + kh) * 66 + kw + l15) * CPAD + c0 + quad * 8;
        #pragma unroll
        for (int nt = 0; nt < 4; nt++) {
            bf16x8 bfrag = *(const bf16x8*)(Bb + nt * 16 * CPAD);
            #pragma unroll
            for (int mt = 0; mt < 4; mt++)
                acc[mt][nt] = __builtin_amdgcn_mfma_f32_16x16x32_bf16(
                    Abuf[ks % 3][mt], bfrag, acc[mt][nt], 0, 0, 0);
        }
    }

    // epilogue: D row = quad*4 + reg, col = l15
    int h = h0 + wj;
    float* ob = out + ((size_t)b * O_ + wi * 64) * HW + h * W_;
    #pragma unroll
    for (int mt = 0; mt < 4; mt++) {
        #pragma unroll
        for (int nt = 0; nt < 4; nt++) {
            int w = nt * 16 + l15;
            #pragma unroll
            for (int r = 0; r < 4; r++) {
                int oo = mt * 16 + quad * 4 + r;
                ob[(size_t)oo * HW + w] = acc[mt][nt][r];
            }
        }
    }
}

// ---------------------------------------------------------------------------
// Launch (4 kernels)
// ---------------------------------------------------------------------------
extern "C" void kernel_launch(void* const* d_in, const int* in_sizes, int n_in,
                              void* d_out, int out_size, void* d_ws, size_t ws_size,
                              hipStream_t stream) {
    const float* x  = (const float*)d_in[0];
    const float* W1 = (const float*)d_in[1];
    const float* b1 = (const float*)d_in[2];
    const float* W2 = (const float*)d_in[3];
    const float* b2 = (const float*)d_in[4];
    const float* Wf = (const float*)d_in[5];
    const float* bf = (const float*)d_in[6];
    float* out = (float*)d_out;

    // Workspace layout:
    //   gap_part : 64*32*64 f32   @ 0        (512 KB)
    //   f2       : 2048 f32       @ 512 KB
    //   kbf      : 32*73728 bf16  @ 528 KB   (4.72 MB)
    //   xT       : 32*64*64*64 bf16 @ ~5.26 MB (16.8 MB)
    float*  gap_part = (float*)d_ws;
    float*  f2       = (float*)((char*)d_ws + 524288);
    __bf16* kbf      = (__bf16*)((char*)d_ws + 540672);
    __bf16* xT       = (__bf16*)((char*)d_ws + 540672 + (size_t)B_ * KJ * 2);

    transpose_gap<<<B_ * H_, 256, 0, stream>>>(x, xT, gap_part);
    mlp_kernel<<<B_, 64, 0, stream>>>(gap_part, W1, b1, W2, b2, f2);
    kergen_kernel<<<O_, 576, 0, stream>>>(f2, Wf, bf, kbf);
    conv_mfma<<<dim3(32, B_), 256, 0, stream>>>(xT, kbf, out);
}

// Round 4
// 149.674 us; speedup vs baseline: 1.4402x; 1.4402x over previous
//
#include <hip/hip_runtime.h>

// Problem constants
#define B_  32
#define C_  64
#define H_  64
#define W_  64
#define O_  128
#define LAT 64
#define HW  (H_*W_)
#define KJ  (O_*C_*9)      // 73728
#define KTOT 576           // C_*9, GEMM K per batch
#define NKS 18             // K steps of 32

typedef __bf16 bf16x8 __attribute__((ext_vector_type(8)));
typedef float  f32x4  __attribute__((ext_vector_type(4)));

// ---------------------------------------------------------------------------
// Stage 1: transpose x -> xT[b][h][w][c] bf16, plus per-(b,h,c) row sums.
// ---------------------------------------------------------------------------
__global__ __launch_bounds__(256) void transpose_gap(const float* __restrict__ x,
                                                     __bf16* __restrict__ xT,
                                                     float* __restrict__ gap_part) {
    int bh = blockIdx.x, b = bh >> 6, h = bh & 63;
    __shared__ float lt[64 * 65];
    int t = threadIdx.x;
    int cc0 = t >> 4, w4 = (t & 15) * 4;

    #pragma unroll
    for (int i = 0; i < 4; i++) {
        int cc = cc0 + 16 * i;
        float4 v = *(const float4*)(x + (((size_t)(b * C_ + cc) * H_) + h) * W_ + w4);
        lt[cc * 65 + w4 + 0] = v.x;
        lt[cc * 65 + w4 + 1] = v.y;
        lt[cc * 65 + w4 + 2] = v.z;
        lt[cc * 65 + w4 + 3] = v.w;
        float s = (v.x + v.y) + (v.z + v.w);
        s += __shfl_xor(s, 1); s += __shfl_xor(s, 2);
        s += __shfl_xor(s, 4); s += __shfl_xor(s, 8);
        if ((t & 15) == 0) gap_part[h * 2048 + b * 64 + cc] = s;
    }
    __syncthreads();

    __bf16* dst = xT + ((size_t)(b * H_ + h) * W_) * C_;
    #pragma unroll
    for (int k = 0; k < 2; k++) {
        int chunk = t + k * 256;
        int w = chunk >> 3, c8 = chunk & 7;
        __bf16 g[8];
        #pragma unroll
        for (int i = 0; i < 8; i++) g[i] = (__bf16)lt[(c8 * 8 + i) * 65 + w];
        *(int4*)(dst + w * C_ + c8 * 8) = *(int4*)g;
    }
}

// ---------------------------------------------------------------------------
// Stage 2: gap reduction + MLP. Writes f2 TRANSPOSED: f2t[l][b] so kergen
// can read 16 consecutive per-b values with block-uniform s_loads.
// ---------------------------------------------------------------------------
__global__ __launch_bounds__(64) void mlp_kernel(const float* __restrict__ gap_part,
                                                 const float* __restrict__ W1,
                                                 const float* __restrict__ b1,
                                                 const float* __restrict__ W2,
                                                 const float* __restrict__ b2,
                                                 float* __restrict__ f2t) {
    int b = blockIdx.x, j = threadIdx.x;
    float s = 0.f;
    #pragma unroll 16
    for (int h = 0; h < 64; h++) s += gap_part[h * 2048 + b * 64 + j];
    __shared__ float g[LAT], f1[LAT];
    g[j] = s * (1.0f / (float)HW);
    __syncthreads();
    float acc = b1[j];
    #pragma unroll 8
    for (int l = 0; l < LAT; l++) acc = fmaf(g[l], W1[l * LAT + j], acc);
    f1[j] = fmaxf(acc, 0.f);
    __syncthreads();
    float acc2 = b2[j];
    #pragma unroll 8
    for (int l = 0; l < LAT; l++) acc2 = fmaf(f1[l], W2[l * LAT + j], acc2);
    f2t[j * B_ + b] = fmaxf(acc2, 0.f);       // transposed store
}

// ---------------------------------------------------------------------------
// Stage 3: kernel generator -> bf16, conv-native layout
//   kbf2[b][ks][o][kk],  ks = tap*2 + (c>=32), kk = c&31   (k = ks*32+kk)
// Grid: 256 blocks = (o = bx&127, bhalf = bx>>7), 576 threads, acc[16].
// Wf loads batched 8-deep (coalesced); f2t reads are block-uniform -> s_load.
// Write-out via LDS shuffle -> consecutive lanes write consecutive kk:
// every wave store covers full 64B lines.
// ---------------------------------------------------------------------------
#define KGP2 592
__global__ __launch_bounds__(576) void kergen_kernel(const float* __restrict__ f2t,
                                                     const float* __restrict__ Wf,
                                                     const float* __restrict__ bfv,
                                                     __bf16* __restrict__ kbf2) {
    int o = blockIdx.x & 127, b0 = (blockIdx.x >> 7) * 16;
    int t = threadIdx.x;
    __shared__ __bf16 ltk[16 * KGP2];          // 18.9 KB

    int j = o * KTOT + t;
    float acc[16];
    float base = bfv[j];
    #pragma unroll
    for (int i = 0; i < 16; i++) acc[i] = base;

    for (int l8 = 0; l8 < LAT; l8 += 8) {
        float w8[8];
        #pragma unroll
        for (int i = 0; i < 8; i++) w8[i] = Wf[(size_t)(l8 + i) * KJ + j];
        #pragma unroll
        for (int i = 0; i < 8; i++) {
            #pragma unroll
            for (int bb = 0; bb < 16; bb++)
                acc[bb] = fmaf(f2t[(l8 + i) * B_ + b0 + bb], w8[i], acc[bb]);
        }
    }

    int c = t / 9, tap = t - c * 9;
    int tpp = (tap * 2 + (c >> 5)) * 32 + (c & 31);
    #pragma unroll
    for (int bb = 0; bb < 16; bb++) ltk[bb * KGP2 + tpp] = (__bf16)acc[bb];
    __syncthreads();
    int ks = t >> 5, kk = t & 31;
    #pragma unroll
    for (int bb = 0; bb < 16; bb++)
        kbf2[(((size_t)(b0 + bb) * NKS + ks) * O_ + o) * 32 + kk] = ltk[bb * KGP2 + t];
}

// ---------------------------------------------------------------------------
// Stage 4: implicit-GEMM MFMA conv. M=128 o, N=128 px (2 rows), K=576.
// Depth-2 register prefetch of A (3-buffer rotation). launch_bounds(256,3)
// -> 170 reg/thread cap: 64 acc + 48 A + misc fits, NO scratch spill
// (round-3 lesson: (256,4)'s 128-reg cap forced Abuf to scratch: WRITE_SIZE
// 66->186 MB). A loads are 1KB contiguous per wave in the kbf2 layout.
// XCD swizzle: htile = (bx&7)*4 + (bx>>3) gives each XCD 4 contiguous
// h-tiles per b -> halo rows L2-local.
// ---------------------------------------------------------------------------
#define CPAD 72
#define ROWE (66 * CPAD)

__global__ __launch_bounds__(256, 3) void conv_mfma(const __bf16* __restrict__ xT,
                                                    const __bf16* __restrict__ kbf2,
                                                    float* __restrict__ out) {
    int b  = blockIdx.y;
    int bx = blockIdx.x;
    int htile = (bx & 7) * 4 + (bx >> 3);      // XCD-local h-tile grouping
    int h0 = htile * 2;
    __shared__ __bf16 xs[4 * ROWE];
    int tid = threadIdx.x;

    // zero halo columns w'=0 and w'=65
    if (tid < 64) {
        int r = tid >> 4, which = (tid >> 3) & 1, c8 = tid & 7;
        *(int4*)(xs + (r * 66 + which * 65) * CPAD + c8 * 8) = int4{0, 0, 0, 0};
    }
    // zero OOB rows (edge blocks only)
    if (h0 == 0) {
        for (int i = tid; i < ROWE / 8; i += 256)
            *(int4*)(xs + i * 8) = int4{0, 0, 0, 0};
    }
    if (h0 == H_ - 2) {
        for (int i = tid; i < ROWE / 8; i += 256)
            *(int4*)(xs + 3 * ROWE + i * 8) = int4{0, 0, 0, 0};
    }

    // stage rows h0-1 .. h0+2
    #pragma unroll
    for (int i = 0; i < 8; i++) {
        int chunk = tid + i * 256;
        int c8 = chunk & 7, w = (chunk >> 3) & 63, r = chunk >> 9;
        int hh = h0 - 1 + r;
        if ((unsigned)hh < (unsigned)H_) {
            int4 v = *(const int4*)(xT + ((size_t)(b * H_ + hh) * W_ + w) * C_ + c8 * 8);
            *(int4*)(xs + (r * 66 + w + 1) * CPAD + c8 * 8) = v;
        }
    }
    __syncthreads();

    int wave = tid >> 6, lane = tid & 63;
    int wi = wave >> 1, wj = wave & 1;
    int l15 = lane & 15, quad = lane >> 4;

    const __bf16* kbA = kbf2 + (size_t)b * (NKS * O_ * 32);
    int mrow = wi * 64 + l15;                  // +mt*16

    f32x4 acc[4][4];
    #pragma unroll
    for (int mt = 0; mt < 4; mt++)
        #pragma unroll
        for (int nt = 0; nt < 4; nt++)
            acc[mt][nt] = (f32x4){0.f, 0.f, 0.f, 0.f};

    bf16x8 Abuf[3][4];
    #pragma unroll
    for (int d = 0; d < 2; d++)
        #pragma unroll
        for (int mt = 0; mt < 4; mt++)
            Abuf[d][mt] = *(const bf16x8*)(kbA + d * (O_ * 32) +
                                           (mrow + mt * 16) * 32 + quad * 8);

    #pragma unroll
    for (int ks = 0; ks < NKS; ks++) {
        if (ks < NKS - 2) {
            #pragma unroll
            for (int mt = 0; mt < 4; mt++)
                Abuf[(ks + 2) % 3][mt] = *(const bf16x8*)(kbA + (ks + 2) * (O_ * 32) +
                                                          (mrow + mt * 16) * 32 + quad * 8);
        }
        int tap = ks >> 1;                     // compile-time after unroll
        int kh = tap / 3, kw = tap - kh * 3;
        int c0 = (ks & 1) * 32;
        const __bf16* Bb = xs + ((wj + kh) * 66 + kw + l15) * CPAD + c0 + quad * 8;
        #pragma unroll
        for (int nt = 0; nt < 4; nt++) {
            bf16x8 bfrag = *(const bf16x8*)(Bb + nt * 16 * CPAD);
            #pragma unroll
            for (int mt = 0; mt < 4; mt++)
                acc[mt][nt] = __builtin_amdgcn_mfma_f32_16x16x32_bf16(
                    Abuf[ks % 3][mt], bfrag, acc[mt][nt], 0, 0, 0);
        }
    }

    // epilogue: D row = quad*4 + reg, col = l15
    int h = h0 + wj;
    float* ob = out + ((size_t)b * O_ + wi * 64) * HW + h * W_;
    #pragma unroll
    for (int mt = 0; mt < 4; mt++) {
        #pragma unroll
        for (int nt = 0; nt < 4; nt++) {
            int w = nt * 16 + l15;
            #pragma unroll
            for (int r = 0; r < 4; r++) {
                int oo = mt * 16 + quad * 4 + r;
                ob[(size_t)oo * HW + w] = acc[mt][nt][r];
            }
        }
    }
}

// ---------------------------------------------------------------------------
// Launch (4 kernels)
// ---------------------------------------------------------------------------
extern "C" void kernel_launch(void* const* d_in, const int* in_sizes, int n_in,
                              void* d_out, int out_size, void* d_ws, size_t ws_size,
                              hipStream_t stream) {
    const float* x  = (const float*)d_in[0];
    const float* W1 = (const float*)d_in[1];
    const float* b1 = (const float*)d_in[2];
    const float* W2 = (const float*)d_in[3];
    const float* b2 = (const float*)d_in[4];
    const float* Wf = (const float*)d_in[5];
    const float* bf = (const float*)d_in[6];
    float* out = (float*)d_out;

    // Workspace layout:
    //   gap_part : 64*32*64 f32     @ 0         (512 KB)
    //   f2t      : 64*32 f32        @ 512 KB    (8 KB)
    //   kbf2     : 32*18*128*32 bf16 @ 528 KB   (4.72 MB)
    //   xT       : 32*64*64*64 bf16 @ ~5.25 MB  (16.8 MB)
    float*  gap_part = (float*)d_ws;
    float*  f2t      = (float*)((char*)d_ws + 524288);
    __bf16* kbf2     = (__bf16*)((char*)d_ws + 540672);
    __bf16* xT       = (__bf16*)((char*)d_ws + 540672 + (size_t)B_ * NKS * O_ * 32 * 2);

    transpose_gap<<<B_ * H_, 256, 0, stream>>>(x, xT, gap_part);
    mlp_kernel<<<B_, 64, 0, stream>>>(gap_part, W1, b1, W2, b2, f2t);
    kergen_kernel<<<256, 576, 0, stream>>>(f2t, Wf, bf, kbf2);
    conv_mfma<<<dim3(32, B_), 256, 0, stream>>>(xT, kbf2, out);
}